// Round 6
// baseline (239.893 us; speedup 1.0000x reference)
//
#include <hip/hip_runtime.h>

// Self-attention forward. Inputs f32: x[4,2048,1024], Wqkv[1024,3072],
// bqkv[3072], Wout[1024,1024], bout[1024]; mask[4,2048,2048] int32.
// Output f32 [4,2048,1024].
//
// Round-12: controlled ablation, zero extra dispatches. Five schedule
// variants (r0 gemm128 + four gemm256 pipelines) all sit at 420-630 TF,
// MfmaUtil 24-27%, conflicts 0, HBM <25% -- phrasing is not the lever.
//  Arm V1 (K1): r5 8-phase gemm256 WITHOUT setprio (isolates T5; baseline
//    81.9 +- 2 us over rounds 2/3/5).
//  Arm V2 (K2): gemm256s -- 2-phase single-buffer 256^2 (r0 structure
//    scaled up): stage tile -> __syncthreads -> compiler-scheduled
//    reads+MFMA -> __syncthreads. 64 KiB LDS, no asm waits, no pipeline.
//    (K2 baseline 77-81 us.)
//  K4/K5: proven gemm128 r0.

typedef __attribute__((ext_vector_type(8))) short short8;
typedef __attribute__((ext_vector_type(4))) float f32x4;
typedef unsigned short u16;

#define SEQ 2048
#define NB 4

static __device__ __forceinline__ u16 f2bf(float f) {
    unsigned int u = __builtin_bit_cast(unsigned int, f);
    u += 0x7fffu + ((u >> 16) & 1u);   // RNE
    return (u16)(u >> 16);
}
static __device__ __forceinline__ float bf2f(u16 h) {
    unsigned int u = ((unsigned int)h) << 16;
    return __builtin_bit_cast(float, u);
}

// async global->LDS, 16 bytes/lane. LDS dest = wave-uniform base + lane*16.
static __device__ __forceinline__ void gld16(const u16* l, const u16* g) {
    __builtin_amdgcn_global_load_lds(
        (__attribute__((address_space(1))) void*)(g),
        (__attribute__((address_space(3))) void*)(l),
        16, 0, 0);
}

// f32 -> bf16, 8 elems/thread.
__global__ __launch_bounds__(256) void cvt_bf16(const float* __restrict__ s,
                                                u16* __restrict__ d, long n) {
    long i = ((long)blockIdx.x * 256 + threadIdx.x) * 8;
    if (i >= n) return;
    f32x4 a = *(const f32x4*)(s + i);
    f32x4 b = *(const f32x4*)(s + i + 4);
    short8 o;
    o[0] = (short)f2bf(a.x); o[1] = (short)f2bf(a.y);
    o[2] = (short)f2bf(a.z); o[3] = (short)f2bf(a.w);
    o[4] = (short)f2bf(b.x); o[5] = (short)f2bf(b.y);
    o[6] = (short)f2bf(b.z); o[7] = (short)f2bf(b.w);
    *(short8*)(d + i) = o;
}

// f32 [R][C] -> bf16 [C][R] (transpose + convert), 32x32 LDS tiles.
__global__ __launch_bounds__(256) void transpose_cvt(const float* __restrict__ in,
                                                     u16* __restrict__ out,
                                                     int R, int C) {
    __shared__ float t[32][33];
    const int c0 = blockIdx.x * 32;
    const int r0 = blockIdx.y * 32;
    const int x = threadIdx.x & 31;
    const int y = (threadIdx.x >> 5) * 4;
    #pragma unroll
    for (int i = 0; i < 4; i++)
        t[y + i][x] = in[(long)(r0 + y + i) * C + c0 + x];
    __syncthreads();
    #pragma unroll
    for (int i = 0; i < 4; i++)
        out[(long)(c0 + y + i) * R + r0 + x] = f2bf(t[x][y + i]);
}

// V slice of qkv (per batch [2048 s][1024 d], row stride 3072, col offset 2048)
// -> vt [b][1024 d][2048 s]. bf16 32x32 tile transpose.
__global__ __launch_bounds__(256) void transpose_v(const u16* __restrict__ qkv,
                                                   u16* __restrict__ vt) {
    __shared__ u16 t[32][33];
    const int b = blockIdx.z;
    const int s0 = blockIdx.y * 32;
    const int d0 = blockIdx.x * 32;
    const int x = threadIdx.x & 31;
    const int y = (threadIdx.x >> 5) * 4;
    const u16* src = qkv + (long)b * SEQ * 3072 + 2048;
    u16* dst = vt + (long)b * 1024 * SEQ;
    #pragma unroll
    for (int i = 0; i < 4; i++)
        t[y + i][x] = src[(long)(s0 + y + i) * 3072 + d0 + x];
    __syncthreads();
    #pragma unroll
    for (int i = 0; i < 4; i++)
        dst[(long)(d0 + y + i) * SEQ + s0 + x] = t[x][y + i];
}

// ============================ gemm256 (V1: 8-phase, PRIO toggle) ===========
// 256x256 tile, BK=64, 512 threads = 8 waves (2M x 4N), per-wave 128x64 out
// = acc[8][4] f32x4. LDS 128 KiB lds[2 slot][4 regions][8192 u16];
// regions: 0=A-lo 1=A-hi 2=B-lo 3=B-hi; slot = tile&1. T2 swizzle: 16B slot
// ^= (region_row&7), pre-swizzled global src on stage, swizzled ds_read.
// r5 schedule (see round-11 header comment for full ledger); PRIO=0 removes
// the setprio(1) wrap around MFMA clusters (this round's K1 ablation arm).
template<int EPI, int PRIO>
__global__ __launch_bounds__(512) void gemm256(
    const u16* __restrict__ Ap, long lda, long aBatch,
    const u16* __restrict__ Bp, long ldb, long bBatch,
    void* __restrict__ Cp, long ldc, long cBatch,
    const float* __restrict__ bias, float scale, int K, int nbx)
{
    __shared__ __attribute__((aligned(16))) u16 lds[2][4][8192];

    const int T = K >> 6;
    const int tid = threadIdx.x;
    const int lane = tid & 63;
    const int wave = tid >> 6;
    const int wm = wave >> 2;          // 0..1
    const int wn = wave & 3;           // 0..3
    const int m16 = lane & 15;
    const int quad = lane >> 4;
    const int b = blockIdx.z;

    // T1: bijective XCD swizzle (nwg % 8 == 0 for all launches here)
    const int nwg = gridDim.x;
    int wg = blockIdx.x;
    if ((nwg & 7) == 0)
        wg = (wg & 7) * (nwg >> 3) + (wg >> 3);
    const int bx = wg % nbx;
    const int by = wg / nbx;
    const long gm0 = (long)by * 256;
    const long gn0 = (long)bx * 256;

    const u16* A = Ap + (long)b * aBatch;
    const u16* B = Bp + (long)b * bBatch;

    const int rl = lane >> 3;                    // 0..7
    const int lsl = ((lane & 7) ^ rl) * 8;       // pre-swizzled src col (u16)
    const long aR = gm0 + wave * 8 + rl;         // + i*128 + h*64
    const long bR = gn0 + (wave >> 2) * 64 + (wave & 3) * 8 + rl; // + i*128 + h*32

#define STG_A(h, tt) do { \
    const int tc_ = ((tt) < T) ? (tt) : (tt) - 2; \
    const long kc_ = (long)(tc_ << 6); \
    const int sl_ = tc_ & 1; \
    gld16(&lds[sl_][h][wave * 512],       A + (aR + (h) * 64) * lda + kc_ + lsl); \
    gld16(&lds[sl_][h][(8 + wave) * 512], A + (aR + 128 + (h) * 64) * lda + kc_ + lsl); \
} while (0)
#define STG_B(h, tt) do { \
    const int tc_ = ((tt) < T) ? (tt) : (tt) - 2; \
    const long kc_ = (long)(tc_ << 6); \
    const int sl_ = tc_ & 1; \
    gld16(&lds[sl_][2 + (h)][wave * 512],       B + (bR + (h) * 32) * ldb + kc_ + lsl); \
    gld16(&lds[sl_][2 + (h)][(8 + wave) * 512], B + (bR + 128 + (h) * 32) * ldb + kc_ + lsl); \
} while (0)

    const int s0 = quad ^ (m16 & 7);
    const int aBase = (wm * 64 + m16) * 64;
    const int bBase = (wn * 32 + m16) * 64;
    const int aoff0 = aBase + s0 * 8, aoff1 = aBase + (s0 ^ 4) * 8;
    const int boff0 = bBase + s0 * 8, boff1 = bBase + (s0 ^ 4) * 8;

    short8 aF[4][2], b0F[2][2], b1F[2][2];
    f32x4 acc[8][4];
    #pragma unroll
    for (int mi = 0; mi < 8; mi++)
        #pragma unroll
        for (int ni = 0; ni < 4; ni++)
            acc[mi][ni] = (f32x4){0.f, 0.f, 0.f, 0.f};

#define LD_A(sl, h) do { \
    const u16* p_ = &lds[sl][h][0]; \
    _Pragma("unroll") \
    for (int mfl_ = 0; mfl_ < 4; ++mfl_) { \
        aF[mfl_][0] = *(const short8*)(p_ + aoff0 + mfl_ * 1024); \
        aF[mfl_][1] = *(const short8*)(p_ + aoff1 + mfl_ * 1024); \
    } \
} while (0)
#define LD_B(sl, h, BF) do { \
    const u16* p_ = &lds[sl][2 + (h)][0]; \
    _Pragma("unroll") \
    for (int nj_ = 0; nj_ < 2; ++nj_) { \
        BF[nj_][0] = *(const short8*)(p_ + boff0 + nj_ * 1024); \
        BF[nj_][1] = *(const short8*)(p_ + boff1 + nj_ * 1024); \
    } \
} while (0)
#define MFMAQ(mh, nh, BF) do { \
    _Pragma("unroll") \
    for (int mi_ = 0; mi_ < 4; ++mi_) \
    _Pragma("unroll") \
    for (int nj_ = 0; nj_ < 2; ++nj_) { \
        acc[(mh)*4+mi_][(nh)*2+nj_] = __builtin_amdgcn_mfma_f32_16x16x32_bf16( \
            aF[mi_][0], BF[nj_][0], acc[(mh)*4+mi_][(nh)*2+nj_], 0, 0, 0); \
        acc[(mh)*4+mi_][(nh)*2+nj_] = __builtin_amdgcn_mfma_f32_16x16x32_bf16( \
            aF[mi_][1], BF[nj_][1], acc[(mh)*4+mi_][(nh)*2+nj_], 0, 0, 0); \
    } \
} while (0)
#define BAR() asm volatile("s_barrier" ::: "memory")
#define VM4() asm volatile("s_waitcnt vmcnt(4)" ::: "memory")
#define VM6() asm volatile("s_waitcnt vmcnt(6)" ::: "memory")
#define LGKM8() asm volatile("s_waitcnt lgkmcnt(8)" ::: "memory")
#define LGKM0() asm volatile("s_waitcnt lgkmcnt(0)" ::: "memory")
#define PHASE_MFMA(mh, nh, BF) do { \
    BAR(); LGKM0(); \
    if (PRIO) __builtin_amdgcn_s_setprio(1); \
    MFMAQ(mh, nh, BF); \
    if (PRIO) __builtin_amdgcn_s_setprio(0); \
    BAR(); \
} while (0)

    // prologue: vm(4) after tile0, vm(6) after +3 half-tiles
    STG_A(0, 0); STG_B(0, 0); STG_A(1, 0); STG_B(1, 0);
    VM4();
    STG_A(0, 1); STG_B(0, 1); STG_A(1, 1);
    VM6();
    BAR();

    for (int t = 0; t < T; ++t) {
        const int buf = t & 1;
        LD_A(buf, 0);
        LD_B(buf, 0, b0F);
        STG_B(1, t + 1);
        LGKM8();
        PHASE_MFMA(0, 0, b0F);
        LD_B(buf, 1, b1F);
        STG_A(0, t + 2);
        PHASE_MFMA(0, 1, b1F);
        LD_A(buf, 1);
        STG_B(0, t + 2);
        PHASE_MFMA(1, 0, b0F);
        STG_A(1, t + 2);
        VM6();
        PHASE_MFMA(1, 1, b1F);
    }

    const long row0 = gm0 + wm * 128 + quad * 4;
    if (EPI == 0 || EPI == 1) {
        u16* C = (u16*)Cp + (long)b * cBatch;
        #pragma unroll
        for (int ni = 0; ni < 4; ++ni) {
            const long col = gn0 + wn * 64 + (ni >> 1) * 32 + (ni & 1) * 16 + m16;
            const float bv = (EPI == 0 && bias) ? bias[col] : 0.f;
            #pragma unroll
            for (int mi = 0; mi < 8; ++mi) {
                const long rb = row0 + (mi >> 2) * 64 + (mi & 3) * 16;
                #pragma unroll
                for (int r = 0; r < 4; ++r) {
                    const float vv = (EPI == 1) ? acc[mi][ni][r] * scale
                                                : acc[mi][ni][r] + bv;
                    C[(rb + r) * ldc + col] = f2bf(vv);
                }
            }
        }
    } else {
        float* C = (float*)Cp + (long)b * cBatch;
        #pragma unroll
        for (int ni = 0; ni < 4; ++ni) {
            const long col = gn0 + wn * 64 + (ni >> 1) * 32 + (ni & 1) * 16 + m16;
            const float bv = bias ? bias[col] : 0.f;
            #pragma unroll
            for (int mi = 0; mi < 8; ++mi) {
                const long rb = row0 + (mi >> 2) * 64 + (mi & 3) * 16;
                #pragma unroll
                for (int r = 0; r < 4; ++r)
                    C[(rb + r) * ldc + col] = acc[mi][ni][r] + bv;
            }
        }
    }
#undef STG_A
#undef STG_B
#undef LD_A
#undef LD_B
#undef MFMAQ
#undef BAR
#undef VM4
#undef VM6
#undef LGKM8
#undef LGKM0
#undef PHASE_MFMA
}

// ============================ gemm256s (V2: 2-phase single-buffer) =========
// Same geometry/swizzle/output mapping as gemm256, but the r0-gemm128 sync
// structure scaled to 256^2: per K-tile {stage 8 half-tiles -> __syncthreads
// -> compiler-scheduled ds_reads + 64 MFMA -> __syncthreads}. LDS 64 KiB
// lds[4 regions][8192]. No asm waits, no pipeline, no setprio -- compiler
// inserts all s_waitcnt (G7: it does this well for ds_read->MFMA).
template<int EPI>
__global__ __launch_bounds__(512) void gemm256s(
    const u16* __restrict__ Ap, long lda, long aBatch,
    const u16* __restrict__ Bp, long ldb, long bBatch,
    void* __restrict__ Cp, long ldc, long cBatch,
    const float* __restrict__ bias, float scale, int K, int nbx)
{
    __shared__ __attribute__((aligned(16))) u16 lds[4][8192];

    const int T = K >> 6;
    const int tid = threadIdx.x;
    const int lane = tid & 63;
    const int wave = tid >> 6;
    const int wm = wave >> 2;          // 0..1
    const int wn = wave & 3;           // 0..3
    const int m16 = lane & 15;
    const int quad = lane >> 4;
    const int b = blockIdx.z;

    const int nwg = gridDim.x;
    int wg = blockIdx.x;
    if ((nwg & 7) == 0)
        wg = (wg & 7) * (nwg >> 3) + (wg >> 3);
    const int bx = wg % nbx;
    const int by = wg / nbx;
    const long gm0 = (long)by * 256;
    const long gn0 = (long)bx * 256;

    const u16* A = Ap + (long)b * aBatch;
    const u16* B = Bp + (long)b * bBatch;

    const int rl = lane >> 3;
    const int lsl = ((lane & 7) ^ rl) * 8;
    const long aR = gm0 + wave * 8 + rl;
    const long bR = gn0 + (wave >> 2) * 64 + (wave & 3) * 8 + rl;

    const int s0 = quad ^ (m16 & 7);
    const int aBase = (wm * 64 + m16) * 64;
    const int bBase = (wn * 32 + m16) * 64;
    const int aoff0 = aBase + s0 * 8, aoff1 = aBase + (s0 ^ 4) * 8;
    const int boff0 = bBase + s0 * 8, boff1 = bBase + (s0 ^ 4) * 8;

    short8 aF[4][2], b0F[2][2], b1F[2][2];
    f32x4 acc[8][4];
    #pragma unroll
    for (int mi = 0; mi < 8; mi++)
        #pragma unroll
        for (int ni = 0; ni < 4; ni++)
            acc[mi][ni] = (f32x4){0.f, 0.f, 0.f, 0.f};

    for (int t = 0; t < T; ++t) {
        const long kc = (long)t << 6;
        // stage one full K-tile (per wave: 8 gld16)
        gld16(&lds[0][wave * 512],       A + (aR)       * lda + kc + lsl);
        gld16(&lds[0][(8 + wave) * 512], A + (aR + 128) * lda + kc + lsl);
        gld16(&lds[1][wave * 512],       A + (aR + 64)  * lda + kc + lsl);
        gld16(&lds[1][(8 + wave) * 512], A + (aR + 192) * lda + kc + lsl);
        gld16(&lds[2][wave * 512],       B + (bR)       * ldb + kc + lsl);
        gld16(&lds[2][(8 + wave) * 512], B + (bR + 128) * ldb + kc + lsl);
        gld16(&lds[3][wave * 512],       B + (bR + 32)  * ldb + kc + lsl);
        gld16(&lds[3][(8 + wave) * 512], B + (bR + 160) * ldb + kc + lsl);
        __syncthreads();

        // A-lo quadrants
        #pragma unroll
        for (int mfl = 0; mfl < 4; ++mfl) {
            aF[mfl][0] = *(const short8*)(&lds[0][0] + aoff0 + mfl * 1024);
            aF[mfl][1] = *(const short8*)(&lds[0][0] + aoff1 + mfl * 1024);
        }
        #pragma unroll
        for (int nj = 0; nj < 2; ++nj) {
            b0F[nj][0] = *(const short8*)(&lds[2][0] + boff0 + nj * 1024);
            b0F[nj][1] = *(const short8*)(&lds[2][0] + boff1 + nj * 1024);
            b1F[nj][0] = *(const short8*)(&lds[3][0] + boff0 + nj * 1024);
            b1F[nj][1] = *(const short8*)(&lds[3][0] + boff1 + nj * 1024);
        }
        #pragma unroll
        for (int mi = 0; mi < 4; ++mi)
            #pragma unroll
            for (int nj = 0; nj < 4; ++nj) {
                const short8* bf = (nj < 2) ? &b0F[nj][0] : &b1F[nj - 2][0];
                acc[mi][nj] = __builtin_amdgcn_mfma_f32_16x16x32_bf16(
                    aF[mi][0], bf[0], acc[mi][nj], 0, 0, 0);
                acc[mi][nj] = __builtin_amdgcn_mfma_f32_16x16x32_bf16(
                    aF[mi][1], bf[1], acc[mi][nj], 0, 0, 0);
            }
        // A-hi quadrants
        #pragma unroll
        for (int mfl = 0; mfl < 4; ++mfl) {
            aF[mfl][0] = *(const short8*)(&lds[1][0] + aoff0 + mfl * 1024);
            aF[mfl][1] = *(const short8*)(&lds[1][0] + aoff1 + mfl * 1024);
        }
        #pragma unroll
        for (int mi = 0; mi < 4; ++mi)
            #pragma unroll
            for (int nj = 0; nj < 4; ++nj) {
                const short8* bf = (nj < 2) ? &b0F[nj][0] : &b1F[nj - 2][0];
                acc[4 + mi][nj] = __builtin_amdgcn_mfma_f32_16x16x32_bf16(
                    aF[mi][0], bf[0], acc[4 + mi][nj], 0, 0, 0);
                acc[4 + mi][nj] = __builtin_amdgcn_mfma_f32_16x16x32_bf16(
                    aF[mi][1], bf[1], acc[4 + mi][nj], 0, 0, 0);
            }
        __syncthreads();
    }

    // C-write: acc[mh*4+mi][nh*2+nj] -> rows gm0+wm*128+mh*64+mi*16+quad*4+r,
    // cols gn0+wn*64+nh*32+nj*16+m16. (acc[.][nj] with nj = nh*2+j as above.)
    const long row0 = gm0 + wm * 128 + quad * 4;
    if (EPI == 0 || EPI == 1) {
        u16* C = (u16*)Cp + (long)b * cBatch;
        #pragma unroll
        for (int ni = 0; ni < 4; ++ni) {
            const long col = gn0 + wn * 64 + (ni >> 1) * 32 + (ni & 1) * 16 + m16;
            const float bv = (EPI == 0 && bias) ? bias[col] : 0.f;
            #pragma unroll
            for (int mi = 0; mi < 8; ++mi) {
                const long rb = row0 + (mi >> 2) * 64 + (mi & 3) * 16;
                #pragma unroll
                for (int r = 0; r < 4; ++r) {
                    const float vv = (EPI == 1) ? acc[mi][ni][r] * scale
                                                : acc[mi][ni][r] + bv;
                    C[(rb + r) * ldc + col] = f2bf(vv);
                }
            }
        }
    } else {
        float* C = (float*)Cp + (long)b * cBatch;
        #pragma unroll
        for (int ni = 0; ni < 4; ++ni) {
            const long col = gn0 + wn * 64 + (ni >> 1) * 32 + (ni & 1) * 16 + m16;
            const float bv = bias ? bias[col] : 0.f;
            #pragma unroll
            for (int mi = 0; mi < 8; ++mi) {
                const long rb = row0 + (mi >> 2) * 64 + (mi & 3) * 16;
                #pragma unroll
                for (int r = 0; r < 4; ++r)
                    C[(rb + r) * ldc + col] = acc[mi][ni][r] + bv;
            }
        }
    }
}

// gemm256s's B-quadrant mapping check: LD in gemm256 reads region 2 (B-lo)
// for ni<2 and region 3 (B-hi) for ni>=2 -- mirrored above via the bf
// select; staging rows bR+{0,128} -> region2, bR+{32,160} -> region3 match
// r5's STG_B(0)/STG_B(1). Identical bytes, identical mapping.

// bf16 MFMA GEMM, 128x128 tile, BK=64 (proven r0 kernel; K4/K5).
template<int EPI>
__global__ __launch_bounds__(256) void gemm128(
    const u16* __restrict__ Ap, long lda, long aBatch,
    const u16* __restrict__ Bp, long ldb, long bBatch,
    void* __restrict__ Cp, long ldc, long cBatch,
    const float* __restrict__ bias,
    float scale, int K)
{
    __shared__ __attribute__((aligned(16))) u16 As[128 * 64];
    __shared__ __attribute__((aligned(16))) u16 Bs[128 * 64];

    const int tid = threadIdx.x;
    const int lane = tid & 63;
    const int wave = tid >> 6;
    const int b = blockIdx.z;
    const long m0 = (long)blockIdx.y * 128;
    const long n0 = (long)blockIdx.x * 128;

    const u16* A = Ap + (long)b * aBatch;
    const u16* B = Bp + (long)b * bBatch;

    const int wm = (wave >> 1) * 64;
    const int wn = (wave & 1) * 64;
    const int m16 = lane & 15;
    const int quad = lane >> 4;

    const int srow = lane >> 3;
    const int skk = (lane & 7) * 8;

    f32x4 acc[4][4];
    #pragma unroll
    for (int mi = 0; mi < 4; mi++)
        #pragma unroll
        for (int ni = 0; ni < 4; ni++)
            acc[mi][ni] = (f32x4){0.f, 0.f, 0.f, 0.f};

    for (int k0 = 0; k0 < K; k0 += 64) {
        #pragma unroll
        for (int c = 0; c < 4; c++) {
            const int r = wave * 32 + c * 8 + srow;
            gld16(As + (wave * 4 + c) * 512, A + (m0 + r) * lda + k0 + skk);
            gld16(Bs + (wave * 4 + c) * 512, B + (n0 + r) * ldb + k0 + skk);
        }
        __syncthreads();

        #pragma unroll
        for (int ks = 0; ks < 2; ks++) {
            short8 af[4], bf[4];
            #pragma unroll
            for (int i = 0; i < 4; i++) {
                af[i] = *(const short8*)&As[(wm + i * 16 + m16) * 64 + ks * 32 + quad * 8];
                bf[i] = *(const short8*)&Bs[(wn + i * 16 + m16) * 64 + ks * 32 + quad * 8];
            }
            #pragma unroll
            for (int mi = 0; mi < 4; mi++)
                #pragma unroll
                for (int ni = 0; ni < 4; ni++)
                    acc[mi][ni] = __builtin_amdgcn_mfma_f32_16x16x32_bf16(
                        af[mi], bf[ni], acc[mi][ni], 0, 0, 0);
        }
        __syncthreads();
    }

    const long row_base = m0 + wm + quad * 4;
    if (EPI == 0) {
        u16* C = (u16*)Cp + (long)b * cBatch;
        #pragma unroll
        for (int ni = 0; ni < 4; ni++) {
            const long col = n0 + wn + ni * 16 + m16;
            const float bv = bias ? bias[col] : 0.f;
            #pragma unroll
            for (int mi = 0; mi < 4; mi++)
                #pragma unroll
                for (int r = 0; r < 4; r++)
                    C[(row_base + mi * 16 + r) * ldc + col] = f2bf(acc[mi][ni][r] + bv);
        }
    } else if (EPI == 1) {
        u16* C = (u16*)Cp + (long)b * cBatch;
        #pragma unroll
        for (int ni = 0; ni < 4; ni++) {
            const long col = n0 + wn + ni * 16 + m16;
            #pragma unroll
            for (int mi = 0; mi < 4; mi++)
                #pragma unroll
                for (int r = 0; r < 4; r++)
                    C[(row_base + mi * 16 + r) * ldc + col] = f2bf(acc[mi][ni][r] * scale);
        }
    } else {
        float* C = (float*)Cp + (long)b * cBatch;
        #pragma unroll
        for (int ni = 0; ni < 4; ni++) {
            const long col = n0 + wn + ni * 16 + m16;
            const float bv = bias ? bias[col] : 0.f;
            #pragma unroll
            for (int mi = 0; mi < 4; mi++)
                #pragma unroll
                for (int r = 0; r < 4; r++)
                    C[(row_base + mi * 16 + r) * ldc + col] = acc[mi][ni][r] + bv;
        }
    }
}

// in-place masked row softmax over 2048 bf16 (f32 math). 1 block per row.
// mask==0 -> score := 1e-10 (applied here in f32; coalesced uint4 reads).
__global__ __launch_bounds__(256) void softmax2048(u16* __restrict__ S,
                                                   const int* __restrict__ mask) {
    const long row = blockIdx.x;
    u16* p = S + row * SEQ;
    const int* mrow = mask + row * SEQ;
    const int tid = threadIdx.x;

    short8 v = *(const short8*)(p + tid * 8);
    uint4 mw0 = *(const uint4*)(mrow + tid * 8);
    uint4 mw1 = *(const uint4*)(mrow + tid * 8 + 4);
    const unsigned int* mwv = (const unsigned int*)&mw0;

    float f[8];
    #pragma unroll
    for (int j = 0; j < 8; j++) {
        const unsigned int mv = (j < 4) ? mwv[j] : ((const unsigned int*)&mw1)[j - 4];
        f[j] = (mv == 0u) ? 1e-10f : bf2f((u16)v[j]);
    }

    float m = f[0];
    #pragma unroll
    for (int j = 1; j < 8; j++) m = fmaxf(m, f[j]);
    #pragma unroll
    for (int i = 1; i < 64; i <<= 1) m = fmaxf(m, __shfl_xor(m, i));

    __shared__ float redm[4], reds[4];
    if ((tid & 63) == 0) redm[tid >> 6] = m;
    __syncthreads();
    m = fmaxf(fmaxf(redm[0], redm[1]), fmaxf(redm[2], redm[3]));

    float e[8], s = 0.f;
    #pragma unroll
    for (int j = 0; j < 8; j++) { e[j] = __expf(f[j] - m); s += e[j]; }
    #pragma unroll
    for (int i = 1; i < 64; i <<= 1) s += __shfl_xor(s, i);
    if ((tid & 63) == 0) reds[tid >> 6] = s;
    __syncthreads();
    s = reds[0] + reds[1] + reds[2] + reds[3];

    const float inv = 1.f / s;
    short8 o;
    #pragma unroll
    for (int j = 0; j < 8; j++) o[j] = (short)f2bf(e[j] * inv);
    *(short8*)(p + tid * 8) = o;
}

extern "C" void kernel_launch(void* const* d_in, const int* in_sizes, int n_in,
                              void* d_out, int out_size, void* d_ws, size_t ws_size,
                              hipStream_t stream) {
    const float* x    = (const float*)d_in[0];
    const int*   mask = (const int*)d_in[1];
    const float* Wqkv = (const float*)d_in[2];
    const float* bqkv = (const float*)d_in[3];
    const float* Wout = (const float*)d_in[4];
    const float* bout = (const float*)d_in[5];
    float* out = (float*)d_out;

    char* ws = (char*)d_ws;
    // ws layout, total 102,760,448 bytes:
    //   [0,        16777216) xh  bf16 [8192][1024]          (cvt -> K1)
    //   [16777216, 23068672) wqt bf16 [3072][1024]          (cvt -> K1)
    //   [0,        33554432) sc  bf16 [4][2048][2048]       (K2 -> K4; xh,wqt dead)
    //   [33554432, 35651584) wot bf16 [1024][1024]          (cvt -> K5)
    //   [35651584, 85983232) qkv bf16 [8192][3072]          (K1 -> K2)
    //   [35651584, 52428800) attn bf16 [8192][1024]         (K4 -> K5; qkv dead)
    //   [85983232,102760448) vt  bf16 [4][1024][2048]       (transpose_v -> K4)
    u16* xh   = (u16*)(ws + 0);
    u16* wqt  = (u16*)(ws + 16777216);
    u16* sc   = (u16*)(ws + 0);
    u16* wot  = (u16*)(ws + 33554432);
    u16* qkv  = (u16*)(ws + 35651584);
    u16* attn = (u16*)(ws + 35651584);
    u16* vt   = (u16*)(ws + 85983232);

    cvt_bf16<<<4096, 256, 0, stream>>>(x, xh, 8388608);
    transpose_cvt<<<dim3(96, 32), 256, 0, stream>>>(Wqkv, wqt, 1024, 3072);
    transpose_cvt<<<dim3(32, 32), 256, 0, stream>>>(Wout, wot, 1024, 1024);

    // K1 [V1 arm]: qkv = x @ Wqkv + bqkv (M=8192,N=3072,K=1024), bf16 out.
    // r5 8-phase WITHOUT setprio. grid 12x32 = 384 wgs, nbx = 12.
    gemm256<0, 0><<<dim3(384, 1, 1), 512, 0, stream>>>(
        xh, 1024, 0, wqt, 1024, 0, qkv, 3072, 0, bqkv, 1.f, 1024, 12);

    // V slice -> vt [b][d][s]
    transpose_v<<<dim3(32, 64, NB), 256, 0, stream>>>(qkv, vt);

    // K2 [V2 arm]: sc[b] = (Q[b] @ K[b]^T)/32 (M=N=2048,K=1024), bf16 out.
    // 2-phase single-buffer gemm256s. 8x8 = 64 wgs/batch x 4 = 1 block/CU.
    gemm256s<1><<<dim3(64, 1, NB), 512, 0, stream>>>(
        qkv, 3072, (long)SEQ * 3072, qkv + 1024, 3072, (long)SEQ * 3072,
        sc, SEQ, (long)SEQ * SEQ, nullptr, 0.03125f, 1024, 8);

    // K3: masked softmax rows (mask==0 -> 1e-10, f32 math, bf16 storage)
    softmax2048<<<dim3(NB * SEQ), 256, 0, stream>>>(sc, mask);

    // K4: attn[b] = P[b] @ V[b]   (M=2048, N=1024, K=2048), bf16 out
    gemm128<0><<<dim3(8, 16, NB), 256, 0, stream>>>(
        sc, SEQ, (long)SEQ * SEQ, vt, SEQ, (long)1024 * SEQ,
        attn, 1024, (long)SEQ * 1024, nullptr, 1.f, 2048);

    // K5: out = attn @ Wout + bout   (M=8192, N=1024, K=1024), f32 out
    gemm128<2><<<dim3(8, 64, 1), 256, 0, stream>>>(
        attn, 1024, 0, wot, 1024, 0, out, 1024, 0, bout, 1.f, 1024);
}

// Round 7
// 221.442 us; speedup vs baseline: 1.0833x; 1.0833x over previous
//
#include <hip/hip_runtime.h>

// Self-attention forward. Inputs f32: x[4,2048,1024], Wqkv[1024,3072],
// bqkv[3072], Wout[1024,1024], bout[1024]; mask[4,2048,2048] int32.
// Output f32 [4,2048,1024].
//
// Round-13: ablation verdict from round 12: 8-phase pipelines == 2-phase
// single-buffer (74-77us both); setprio inert. Common denominator: stage->
// consume gap ~0 at every barrier -> full staging latency exposed per tile.
// New gemm256d = round-12's PASSING gemm256s body + LDS double-buffer with
// stage of tile t+1 issued BEFORE tile t's ~2500cy MFMA cluster and ONE
// __syncthreads per tile (its builtin vmcnt(0) waits on loads issued a
// full tile earlier -> latency covered; catalog T3 "minimum 2-phase").
// Plus: epilogue loop order swapped to (mi,r) outer / ni inner -- the 4
// stores filling one 128B line issue back-to-back (round-12 K1 counters:
// WRITE_SIZE 90.5 MB vs 50.3 ideal = partial-line eviction). Same fix in
// gemm128 (K4/K5).

typedef __attribute__((ext_vector_type(8))) short short8;
typedef __attribute__((ext_vector_type(4))) float f32x4;
typedef unsigned short u16;

#define SEQ 2048
#define NB 4

static __device__ __forceinline__ u16 f2bf(float f) {
    unsigned int u = __builtin_bit_cast(unsigned int, f);
    u += 0x7fffu + ((u >> 16) & 1u);   // RNE
    return (u16)(u >> 16);
}
static __device__ __forceinline__ float bf2f(u16 h) {
    unsigned int u = ((unsigned int)h) << 16;
    return __builtin_bit_cast(float, u);
}

// async global->LDS, 16 bytes/lane. LDS dest = wave-uniform base + lane*16.
static __device__ __forceinline__ void gld16(const u16* l, const u16* g) {
    __builtin_amdgcn_global_load_lds(
        (__attribute__((address_space(1))) void*)(g),
        (__attribute__((address_space(3))) void*)(l),
        16, 0, 0);
}

// f32 -> bf16, 8 elems/thread.
__global__ __launch_bounds__(256) void cvt_bf16(const float* __restrict__ s,
                                                u16* __restrict__ d, long n) {
    long i = ((long)blockIdx.x * 256 + threadIdx.x) * 8;
    if (i >= n) return;
    f32x4 a = *(const f32x4*)(s + i);
    f32x4 b = *(const f32x4*)(s + i + 4);
    short8 o;
    o[0] = (short)f2bf(a.x); o[1] = (short)f2bf(a.y);
    o[2] = (short)f2bf(a.z); o[3] = (short)f2bf(a.w);
    o[4] = (short)f2bf(b.x); o[5] = (short)f2bf(b.y);
    o[6] = (short)f2bf(b.z); o[7] = (short)f2bf(b.w);
    *(short8*)(d + i) = o;
}

// f32 [R][C] -> bf16 [C][R] (transpose + convert), 32x32 LDS tiles.
__global__ __launch_bounds__(256) void transpose_cvt(const float* __restrict__ in,
                                                     u16* __restrict__ out,
                                                     int R, int C) {
    __shared__ float t[32][33];
    const int c0 = blockIdx.x * 32;
    const int r0 = blockIdx.y * 32;
    const int x = threadIdx.x & 31;
    const int y = (threadIdx.x >> 5) * 4;
    #pragma unroll
    for (int i = 0; i < 4; i++)
        t[y + i][x] = in[(long)(r0 + y + i) * C + c0 + x];
    __syncthreads();
    #pragma unroll
    for (int i = 0; i < 4; i++)
        out[(long)(c0 + y + i) * R + r0 + x] = f2bf(t[x][y + i]);
}

// V slice of qkv (per batch [2048 s][1024 d], row stride 3072, col offset 2048)
// -> vt [b][1024 d][2048 s]. bf16 32x32 tile transpose.
__global__ __launch_bounds__(256) void transpose_v(const u16* __restrict__ qkv,
                                                   u16* __restrict__ vt) {
    __shared__ u16 t[32][33];
    const int b = blockIdx.z;
    const int s0 = blockIdx.y * 32;
    const int d0 = blockIdx.x * 32;
    const int x = threadIdx.x & 31;
    const int y = (threadIdx.x >> 5) * 4;
    const u16* src = qkv + (long)b * SEQ * 3072 + 2048;
    u16* dst = vt + (long)b * 1024 * SEQ;
    #pragma unroll
    for (int i = 0; i < 4; i++)
        t[y + i][x] = src[(long)(s0 + y + i) * 3072 + d0 + x];
    __syncthreads();
    #pragma unroll
    for (int i = 0; i < 4; i++)
        dst[(long)(d0 + y + i) * SEQ + s0 + x] = t[x][y + i];
}

// ============================ gemm256d =====================================
// 256x256 tile, BK=64, 512 threads = 8 waves (2M x 4N), per-wave 128x64 out
// = acc[8][4] f32x4. C[m][n] = sum_k A[m][k]*B[n][k] (B is [N][K] row-major).
// LDS 128 KiB: lds[2 buf][4 regions][8192 u16]; regions 0=A-lo 1=A-hi
// 2=B-lo 3=B-hi (each 128 rows x 64 k). T2 swizzle: 16B slot ^= (row&7),
// pre-swizzled global src col on stage, swizzled ds_read addr.
// Minimum-2-phase double-buffer loop (catalog T3 recipe):
//   prologue: STGD(buf0, tile0); __syncthreads();
//   tile t:   STGD(buf^1, t+1) [8 gld16, skipped on last tile];
//             ds_read frags from buf; 64 MFMA (compiler-scheduled);
//             __syncthreads();  // builtin vmcnt(0): drains t+1's stage,
//                               // issued ~2500cy ago -> latency covered;
//                               // lgkmcnt(0): all waves' buf reads done
//                               // before next tile overwrites buf^1? no --
//                               // overwrite target is buf^1 staged BEFORE
//                               // this sync; its reads completed at the
//                               // PREVIOUS sync. Ledger: reads of buf X in
//                               // tile t; stage into X at top of t+1 (after
//                               // t's sync drained all reads of X). Safe.
//   buf ^= 1;
// T loop unrolled x2 so buf is compile-time (T even: K=1024 -> 16).
// Epilogue: (mi,r) outer / ni inner -- 4 stores per 128B line back-to-back.
template<int EPI>
__global__ __launch_bounds__(512) void gemm256d(
    const u16* __restrict__ Ap, long lda, long aBatch,
    const u16* __restrict__ Bp, long ldb, long bBatch,
    void* __restrict__ Cp, long ldc, long cBatch,
    const float* __restrict__ bias, float scale, int K, int nbx)
{
    __shared__ __attribute__((aligned(16))) u16 lds[2][4][8192];

    const int T = K >> 6;              // even
    const int tid = threadIdx.x;
    const int lane = tid & 63;
    const int wave = tid >> 6;
    const int wm = wave >> 2;          // 0..1
    const int wn = wave & 3;           // 0..3
    const int m16 = lane & 15;
    const int quad = lane >> 4;
    const int b = blockIdx.z;

    // T1: bijective XCD swizzle (nwg % 8 == 0 for all launches here)
    const int nwg = gridDim.x;
    int wg = blockIdx.x;
    if ((nwg & 7) == 0)
        wg = (wg & 7) * (nwg >> 3) + (wg >> 3);
    const int bx = wg % nbx;
    const int by = wg / nbx;
    const long gm0 = (long)by * 256;
    const long gn0 = (long)bx * 256;

    const u16* A = Ap + (long)b * aBatch;
    const u16* B = Bp + (long)b * bBatch;

    const int rl = lane >> 3;                    // 0..7
    const int lsl = ((lane & 7) ^ rl) * 8;       // pre-swizzled src col (u16)
    const long aR = gm0 + wave * 8 + rl;
    const long bR = gn0 + (wave >> 2) * 64 + (wave & 3) * 8 + rl;

#define STGD(sl, tt) do { \
    const long kc_ = (long)(tt) << 6; \
    u16* l_ = &lds[sl][0][0]; \
    gld16(l_ + 0 * 8192 + wave * 512,       A + (aR)       * lda + kc_ + lsl); \
    gld16(l_ + 0 * 8192 + (8 + wave) * 512, A + (aR + 128) * lda + kc_ + lsl); \
    gld16(l_ + 1 * 8192 + wave * 512,       A + (aR + 64)  * lda + kc_ + lsl); \
    gld16(l_ + 1 * 8192 + (8 + wave) * 512, A + (aR + 192) * lda + kc_ + lsl); \
    gld16(l_ + 2 * 8192 + wave * 512,       B + (bR)       * ldb + kc_ + lsl); \
    gld16(l_ + 2 * 8192 + (8 + wave) * 512, B + (bR + 128) * ldb + kc_ + lsl); \
    gld16(l_ + 3 * 8192 + wave * 512,       B + (bR + 32)  * ldb + kc_ + lsl); \
    gld16(l_ + 3 * 8192 + (8 + wave) * 512, B + (bR + 160) * ldb + kc_ + lsl); \
} while (0)

    // read offsets (u16). 16B slot s ^= (row&7) via s0.
    const int s0 = quad ^ (m16 & 7);
    const int aBase = (wm * 64 + m16) * 64;
    const int bBase = (wn * 32 + m16) * 64;
    const int aoff0 = aBase + s0 * 8, aoff1 = aBase + (s0 ^ 4) * 8;
    const int boff0 = bBase + s0 * 8, boff1 = bBase + (s0 ^ 4) * 8;

    short8 aF[4][2], b0F[2][2], b1F[2][2];
    f32x4 acc[8][4];
    #pragma unroll
    for (int mi = 0; mi < 8; mi++)
        #pragma unroll
        for (int ni = 0; ni < 4; ni++)
            acc[mi][ni] = (f32x4){0.f, 0.f, 0.f, 0.f};

// one tile's compute from buffer sl (verbatim round-12 gemm256s body)
#define TILE_COMPUTE(sl) do { \
    const u16* l = &lds[sl][0][0]; \
    _Pragma("unroll") \
    for (int mfl = 0; mfl < 4; ++mfl) { \
        aF[mfl][0] = *(const short8*)(l + aoff0 + mfl * 1024); \
        aF[mfl][1] = *(const short8*)(l + aoff1 + mfl * 1024); \
    } \
    _Pragma("unroll") \
    for (int nj = 0; nj < 2; ++nj) { \
        b0F[nj][0] = *(const short8*)(l + 2 * 8192 + boff0 + nj * 1024); \
        b0F[nj][1] = *(const short8*)(l + 2 * 8192 + boff1 + nj * 1024); \
        b1F[nj][0] = *(const short8*)(l + 3 * 8192 + boff0 + nj * 1024); \
        b1F[nj][1] = *(const short8*)(l + 3 * 8192 + boff1 + nj * 1024); \
    } \
    _Pragma("unroll") \
    for (int mi = 0; mi < 4; ++mi) \
        _Pragma("unroll") \
        for (int nj = 0; nj < 4; ++nj) { \
            const short8* bf = (nj < 2) ? &b0F[nj][0] : &b1F[nj - 2][0]; \
            acc[mi][nj] = __builtin_amdgcn_mfma_f32_16x16x32_bf16( \
                aF[mi][0], bf[0], acc[mi][nj], 0, 0, 0); \
            acc[mi][nj] = __builtin_amdgcn_mfma_f32_16x16x32_bf16( \
                aF[mi][1], bf[1], acc[mi][nj], 0, 0, 0); \
        } \
    _Pragma("unroll") \
    for (int mfl = 0; mfl < 4; ++mfl) { \
        aF[mfl][0] = *(const short8*)(l + 1 * 8192 + aoff0 + mfl * 1024); \
        aF[mfl][1] = *(const short8*)(l + 1 * 8192 + aoff1 + mfl * 1024); \
    } \
    _Pragma("unroll") \
    for (int mi = 0; mi < 4; ++mi) \
        _Pragma("unroll") \
        for (int nj = 0; nj < 4; ++nj) { \
            const short8* bf = (nj < 2) ? &b0F[nj][0] : &b1F[nj - 2][0]; \
            acc[4 + mi][nj] = __builtin_amdgcn_mfma_f32_16x16x32_bf16( \
                aF[mi][0], bf[0], acc[4 + mi][nj], 0, 0, 0); \
            acc[4 + mi][nj] = __builtin_amdgcn_mfma_f32_16x16x32_bf16( \
                aF[mi][1], bf[1], acc[4 + mi][nj], 0, 0, 0); \
        } \
} while (0)

    // prologue
    STGD(0, 0);
    __syncthreads();

    // main loop, unrolled x2 (T even) so buffer index is compile-time
    for (int t = 0; t < T; t += 2) {
        if (t + 1 < T) STGD(1, t + 1);
        TILE_COMPUTE(0);
        __syncthreads();
        if (t + 2 < T) STGD(0, t + 2);
        TILE_COMPUTE(1);
        __syncthreads();
    }

    // epilogue: (mi,r) outer / ni inner -> 4 line-filling stores adjacent.
    const long row0 = gm0 + wm * 128 + quad * 4;
    const long colbase = gn0 + wn * 64 + m16;
    if (EPI == 0 || EPI == 1) {
        u16* C = (u16*)Cp + (long)b * cBatch;
        float bv[4];
        #pragma unroll
        for (int ni = 0; ni < 4; ++ni)
            bv[ni] = (EPI == 0 && bias)
                   ? bias[colbase + (ni >> 1) * 32 + (ni & 1) * 16] : 0.f;
        #pragma unroll
        for (int mi = 0; mi < 8; ++mi) {
            const long rb = row0 + (mi >> 2) * 64 + (mi & 3) * 16;
            #pragma unroll
            for (int r = 0; r < 4; ++r) {
                u16* Crow = C + (rb + r) * ldc + colbase;
                #pragma unroll
                for (int ni = 0; ni < 4; ++ni) {
                    const float vv = (EPI == 1) ? acc[mi][ni][r] * scale
                                                : acc[mi][ni][r] + bv[ni];
                    Crow[(ni >> 1) * 32 + (ni & 1) * 16] = f2bf(vv);
                }
            }
        }
    } else {
        float* C = (float*)Cp + (long)b * cBatch;
        float bv[4];
        #pragma unroll
        for (int ni = 0; ni < 4; ++ni)
            bv[ni] = bias ? bias[colbase + (ni >> 1) * 32 + (ni & 1) * 16] : 0.f;
        #pragma unroll
        for (int mi = 0; mi < 8; ++mi) {
            const long rb = row0 + (mi >> 2) * 64 + (mi & 3) * 16;
            #pragma unroll
            for (int r = 0; r < 4; ++r) {
                float* Crow = C + (rb + r) * ldc + colbase;
                #pragma unroll
                for (int ni = 0; ni < 4; ++ni)
                    Crow[(ni >> 1) * 32 + (ni & 1) * 16] = acc[mi][ni][r] + bv[ni];
            }
        }
    }
#undef STGD
#undef TILE_COMPUTE
}

// bf16 MFMA GEMM, 128x128 tile, BK=64 (proven r0 structure; K4/K5).
// Epilogue loop order: (mi,r) outer / ni inner (write-combining fix).
template<int EPI>
__global__ __launch_bounds__(256) void gemm128(
    const u16* __restrict__ Ap, long lda, long aBatch,
    const u16* __restrict__ Bp, long ldb, long bBatch,
    void* __restrict__ Cp, long ldc, long cBatch,
    const float* __restrict__ bias,
    float scale, int K)
{
    __shared__ __attribute__((aligned(16))) u16 As[128 * 64];
    __shared__ __attribute__((aligned(16))) u16 Bs[128 * 64];

    const int tid = threadIdx.x;
    const int lane = tid & 63;
    const int wave = tid >> 6;
    const int b = blockIdx.z;
    const long m0 = (long)blockIdx.y * 128;
    const long n0 = (long)blockIdx.x * 128;

    const u16* A = Ap + (long)b * aBatch;
    const u16* B = Bp + (long)b * bBatch;

    const int wm = (wave >> 1) * 64;
    const int wn = (wave & 1) * 64;
    const int m16 = lane & 15;
    const int quad = lane >> 4;

    const int srow = lane >> 3;
    const int skk = (lane & 7) * 8;

    f32x4 acc[4][4];
    #pragma unroll
    for (int mi = 0; mi < 4; mi++)
        #pragma unroll
        for (int ni = 0; ni < 4; ni++)
            acc[mi][ni] = (f32x4){0.f, 0.f, 0.f, 0.f};

    for (int k0 = 0; k0 < K; k0 += 64) {
        #pragma unroll
        for (int c = 0; c < 4; c++) {
            const int r = wave * 32 + c * 8 + srow;
            gld16(As + (wave * 4 + c) * 512, A + (m0 + r) * lda + k0 + skk);
            gld16(Bs + (wave * 4 + c) * 512, B + (n0 + r) * ldb + k0 + skk);
        }
        __syncthreads();

        #pragma unroll
        for (int ks = 0; ks < 2; ks++) {
            short8 af[4], bf[4];
            #pragma unroll
            for (int i = 0; i < 4; i++) {
                af[i] = *(const short8*)&As[(wm + i * 16 + m16) * 64 + ks * 32 + quad * 8];
                bf[i] = *(const short8*)&Bs[(wn + i * 16 + m16) * 64 + ks * 32 + quad * 8];
            }
            #pragma unroll
            for (int mi = 0; mi < 4; mi++)
                #pragma unroll
                for (int ni = 0; ni < 4; ni++)
                    acc[mi][ni] = __builtin_amdgcn_mfma_f32_16x16x32_bf16(
                        af[mi], bf[ni], acc[mi][ni], 0, 0, 0);
        }
        __syncthreads();
    }

    const long row_base = m0 + wm + quad * 4;
    const long colbase = n0 + wn + m16;
    if (EPI == 0) {
        u16* C = (u16*)Cp + (long)b * cBatch;
        float bv[4];
        #pragma unroll
        for (int ni = 0; ni < 4; ni++)
            bv[ni] = bias ? bias[colbase + ni * 16] : 0.f;
        #pragma unroll
        for (int mi = 0; mi < 4; mi++)
            #pragma unroll
            for (int r = 0; r < 4; r++) {
                u16* Crow = C + (row_base + mi * 16 + r) * ldc + colbase;
                #pragma unroll
                for (int ni = 0; ni < 4; ni++)
                    Crow[ni * 16] = f2bf(acc[mi][ni][r] + bv[ni]);
            }
    } else if (EPI == 1) {
        u16* C = (u16*)Cp + (long)b * cBatch;
        #pragma unroll
        for (int mi = 0; mi < 4; mi++)
            #pragma unroll
            for (int r = 0; r < 4; r++) {
                u16* Crow = C + (row_base + mi * 16 + r) * ldc + colbase;
                #pragma unroll
                for (int ni = 0; ni < 4; ni++)
                    Crow[ni * 16] = f2bf(acc[mi][ni][r] * scale);
            }
    } else {
        float* C = (float*)Cp + (long)b * cBatch;
        float bv[4];
        #pragma unroll
        for (int ni = 0; ni < 4; ni++)
            bv[ni] = bias ? bias[colbase + ni * 16] : 0.f;
        #pragma unroll
        for (int mi = 0; mi < 4; mi++)
            #pragma unroll
            for (int r = 0; r < 4; r++) {
                float* Crow = C + (row_base + mi * 16 + r) * ldc + colbase;
                #pragma unroll
                for (int ni = 0; ni < 4; ni++)
                    Crow[ni * 16] = acc[mi][ni][r] + bv[ni];
            }
    }
}

// in-place masked row softmax over 2048 bf16 (f32 math). 1 block per row.
// mask==0 -> score := 1e-10 (applied here in f32; coalesced uint4 reads).
__global__ __launch_bounds__(256) void softmax2048(u16* __restrict__ S,
                                                   const int* __restrict__ mask) {
    const long row = blockIdx.x;
    u16* p = S + row * SEQ;
    const int* mrow = mask + row * SEQ;
    const int tid = threadIdx.x;

    short8 v = *(const short8*)(p + tid * 8);
    uint4 mw0 = *(const uint4*)(mrow + tid * 8);
    uint4 mw1 = *(const uint4*)(mrow + tid * 8 + 4);
    const unsigned int* mwv = (const unsigned int*)&mw0;

    float f[8];
    #pragma unroll
    for (int j = 0; j < 8; j++) {
        const unsigned int mv = (j < 4) ? mwv[j] : ((const unsigned int*)&mw1)[j - 4];
        f[j] = (mv == 0u) ? 1e-10f : bf2f((u16)v[j]);
    }

    float m = f[0];
    #pragma unroll
    for (int j = 1; j < 8; j++) m = fmaxf(m, f[j]);
    #pragma unroll
    for (int i = 1; i < 64; i <<= 1) m = fmaxf(m, __shfl_xor(m, i));

    __shared__ float redm[4], reds[4];
    if ((tid & 63) == 0) redm[tid >> 6] = m;
    __syncthreads();
    m = fmaxf(fmaxf(redm[0], redm[1]), fmaxf(redm[2], redm[3]));

    float e[8], s = 0.f;
    #pragma unroll
    for (int j = 0; j < 8; j++) { e[j] = __expf(f[j] - m); s += e[j]; }
    #pragma unroll
    for (int i = 1; i < 64; i <<= 1) s += __shfl_xor(s, i);
    if ((tid & 63) == 0) reds[tid >> 6] = s;
    __syncthreads();
    s = reds[0] + reds[1] + reds[2] + reds[3];

    const float inv = 1.f / s;
    short8 o;
    #pragma unroll
    for (int j = 0; j < 8; j++) o[j] = (short)f2bf(e[j] * inv);
    *(short8*)(p + tid * 8) = o;
}

extern "C" void kernel_launch(void* const* d_in, const int* in_sizes, int n_in,
                              void* d_out, int out_size, void* d_ws, size_t ws_size,
                              hipStream_t stream) {
    const float* x    = (const float*)d_in[0];
    const int*   mask = (const int*)d_in[1];
    const float* Wqkv = (const float*)d_in[2];
    const float* bqkv = (const float*)d_in[3];
    const float* Wout = (const float*)d_in[4];
    const float* bout = (const float*)d_in[5];
    float* out = (float*)d_out;

    char* ws = (char*)d_ws;
    // ws layout, total 102,760,448 bytes:
    //   [0,        16777216) xh  bf16 [8192][1024]          (cvt -> K1)
    //   [16777216, 23068672) wqt bf16 [3072][1024]          (cvt -> K1)
    //   [0,        33554432) sc  bf16 [4][2048][2048]       (K2 -> K4; xh,wqt dead)
    //   [33554432, 35651584) wot bf16 [1024][1024]          (cvt -> K5)
    //   [35651584, 85983232) qkv bf16 [8192][3072]          (K1 -> K2)
    //   [35651584, 52428800) attn bf16 [8192][1024]         (K4 -> K5; qkv dead)
    //   [85983232,102760448) vt  bf16 [4][1024][2048]       (transpose_v -> K4)
    u16* xh   = (u16*)(ws + 0);
    u16* wqt  = (u16*)(ws + 16777216);
    u16* sc   = (u16*)(ws + 0);
    u16* wot  = (u16*)(ws + 33554432);
    u16* qkv  = (u16*)(ws + 35651584);
    u16* attn = (u16*)(ws + 35651584);
    u16* vt   = (u16*)(ws + 85983232);

    cvt_bf16<<<4096, 256, 0, stream>>>(x, xh, 8388608);
    transpose_cvt<<<dim3(96, 32), 256, 0, stream>>>(Wqkv, wqt, 1024, 3072);
    transpose_cvt<<<dim3(32, 32), 256, 0, stream>>>(Wout, wot, 1024, 1024);

    // K1: qkv = x @ Wqkv + bqkv (M=8192, N=3072, K=1024), bf16 out.
    // gemm256d min-2-phase dbuf: grid 12x32 = 384 wgs, nbx = 12.
    gemm256d<0><<<dim3(384, 1, 1), 512, 0, stream>>>(
        xh, 1024, 0, wqt, 1024, 0, qkv, 3072, 0, bqkv, 1.f, 1024, 12);

    // V slice -> vt [b][d][s]
    transpose_v<<<dim3(32, 64, NB), 256, 0, stream>>>(qkv, vt);

    // K2: sc[b] = (Q[b] @ K[b]^T)/32 (M=N=2048, K=1024), bf16 out.
    // gemm256d: 8x8 = 64 wgs/batch x 4 = 256 wgs = 1 block/CU.
    gemm256d<1><<<dim3(64, 1, NB), 512, 0, stream>>>(
        qkv, 3072, (long)SEQ * 3072, qkv + 1024, 3072, (long)SEQ * 3072,
        sc, SEQ, (long)SEQ * SEQ, nullptr, 0.03125f, 1024, 8);

    // K3: masked softmax rows (mask==0 -> 1e-10, f32 math, bf16 storage)
    softmax2048<<<dim3(NB * SEQ), 256, 0, stream>>>(sc, mask);

    // K4: attn[b] = P[b] @ V[b] (M=2048, N=1024, K=2048), bf16 out
    gemm128<0><<<dim3(8, 16, NB), 256, 0, stream>>>(
        sc, SEQ, (long)SEQ * SEQ, vt, SEQ, (long)1024 * SEQ,
        attn, 1024, (long)SEQ * 1024, nullptr, 1.f, 2048);

    // K5: out = attn @ Wout + bout (M=8192, N=1024, K=1024), f32 out
    gemm128<2><<<dim3(8, 64, 1), 256, 0, stream>>>(
        attn, 1024, 0, wot, 1024, 0, out, 1024, 0, bout, 1.f, 1024);
}

// Round 8
// 198.436 us; speedup vs baseline: 1.2089x; 1.1159x over previous
//
#include <hip/hip_runtime.h>

// Self-attention forward. Inputs f32: x[4,2048,1024], Wqkv[1024,3072],
// bqkv[3072], Wout[1024,1024], bout[1024]; mask[4,2048,2048] int32.
// Output f32 [4,2048,1024].
//
// Round-14: propagate round-13's winning structure (double-buffered LDS,
// stage of tile t+1 issued BEFORE tile t's MFMA cluster, ONE __syncthreads
// per tile, T2 swizzle, write-combined epilogue) from 256^2 (gemm256d:
// K1 77->61.6us, MfmaUtil 33%, WRITE ideal) down to 128^2 for K4/K5.
// gemm128d = direct geometry reduction of gemm256d: 4 waves, 64 KiB LDS ->
// 2 blocks/CU (adds cross-block overlap). No reg read-ahead, no asm waits
// (unlike round-10's failed v2) -- sync is __syncthreads only, exactly the
// structure that passed at 256^2.

typedef __attribute__((ext_vector_type(8))) short short8;
typedef __attribute__((ext_vector_type(4))) float f32x4;
typedef unsigned short u16;

#define SEQ 2048
#define NB 4

static __device__ __forceinline__ u16 f2bf(float f) {
    unsigned int u = __builtin_bit_cast(unsigned int, f);
    u += 0x7fffu + ((u >> 16) & 1u);   // RNE
    return (u16)(u >> 16);
}
static __device__ __forceinline__ float bf2f(u16 h) {
    unsigned int u = ((unsigned int)h) << 16;
    return __builtin_bit_cast(float, u);
}

// async global->LDS, 16 bytes/lane. LDS dest = wave-uniform base + lane*16.
static __device__ __forceinline__ void gld16(const u16* l, const u16* g) {
    __builtin_amdgcn_global_load_lds(
        (__attribute__((address_space(1))) void*)(g),
        (__attribute__((address_space(3))) void*)(l),
        16, 0, 0);
}

// f32 -> bf16, 8 elems/thread.
__global__ __launch_bounds__(256) void cvt_bf16(const float* __restrict__ s,
                                                u16* __restrict__ d, long n) {
    long i = ((long)blockIdx.x * 256 + threadIdx.x) * 8;
    if (i >= n) return;
    f32x4 a = *(const f32x4*)(s + i);
    f32x4 b = *(const f32x4*)(s + i + 4);
    short8 o;
    o[0] = (short)f2bf(a.x); o[1] = (short)f2bf(a.y);
    o[2] = (short)f2bf(a.z); o[3] = (short)f2bf(a.w);
    o[4] = (short)f2bf(b.x); o[5] = (short)f2bf(b.y);
    o[6] = (short)f2bf(b.z); o[7] = (short)f2bf(b.w);
    *(short8*)(d + i) = o;
}

// f32 [R][C] -> bf16 [C][R] (transpose + convert), 32x32 LDS tiles.
__global__ __launch_bounds__(256) void transpose_cvt(const float* __restrict__ in,
                                                     u16* __restrict__ out,
                                                     int R, int C) {
    __shared__ float t[32][33];
    const int c0 = blockIdx.x * 32;
    const int r0 = blockIdx.y * 32;
    const int x = threadIdx.x & 31;
    const int y = (threadIdx.x >> 5) * 4;
    #pragma unroll
    for (int i = 0; i < 4; i++)
        t[y + i][x] = in[(long)(r0 + y + i) * C + c0 + x];
    __syncthreads();
    #pragma unroll
    for (int i = 0; i < 4; i++)
        out[(long)(c0 + y + i) * R + r0 + x] = f2bf(t[x][y + i]);
}

// V slice of qkv (per batch [2048 s][1024 d], row stride 3072, col offset 2048)
// -> vt [b][1024 d][2048 s]. bf16 32x32 tile transpose.
__global__ __launch_bounds__(256) void transpose_v(const u16* __restrict__ qkv,
                                                   u16* __restrict__ vt) {
    __shared__ u16 t[32][33];
    const int b = blockIdx.z;
    const int s0 = blockIdx.y * 32;
    const int d0 = blockIdx.x * 32;
    const int x = threadIdx.x & 31;
    const int y = (threadIdx.x >> 5) * 4;
    const u16* src = qkv + (long)b * SEQ * 3072 + 2048;
    u16* dst = vt + (long)b * 1024 * SEQ;
    #pragma unroll
    for (int i = 0; i < 4; i++)
        t[y + i][x] = src[(long)(s0 + y + i) * 3072 + d0 + x];
    __syncthreads();
    #pragma unroll
    for (int i = 0; i < 4; i++)
        dst[(long)(d0 + y + i) * SEQ + s0 + x] = t[x][y + i];
}

// ============================ gemm256d =====================================
// 256x256 tile, BK=64, 512 threads = 8 waves (2M x 4N), per-wave 128x64 out
// = acc[8][4] f32x4. C[m][n] = sum_k A[m][k]*B[n][k] (B is [N][K] row-major).
// LDS 128 KiB: lds[2 buf][4 regions][8192 u16]; regions 0=A-lo 1=A-hi
// 2=B-lo 3=B-hi (each 128 rows x 64 k). T2 swizzle: 16B slot ^= (row&7),
// pre-swizzled global src col on stage, swizzled ds_read addr.
// Min-2-phase dbuf loop: STGD(buf^1, t+1) before TILE_COMPUTE(buf); one
// __syncthreads per tile (builtin vmcnt(0) drains a stage issued ~2500cy
// earlier -> latency covered). Epilogue (mi,r) outer / ni inner.
template<int EPI>
__global__ __launch_bounds__(512) void gemm256d(
    const u16* __restrict__ Ap, long lda, long aBatch,
    const u16* __restrict__ Bp, long ldb, long bBatch,
    void* __restrict__ Cp, long ldc, long cBatch,
    const float* __restrict__ bias, float scale, int K, int nbx)
{
    __shared__ __attribute__((aligned(16))) u16 lds[2][4][8192];

    const int T = K >> 6;              // even
    const int tid = threadIdx.x;
    const int lane = tid & 63;
    const int wave = tid >> 6;
    const int wm = wave >> 2;          // 0..1
    const int wn = wave & 3;           // 0..3
    const int m16 = lane & 15;
    const int quad = lane >> 4;
    const int b = blockIdx.z;

    // T1: bijective XCD swizzle (nwg % 8 == 0 for all launches here)
    const int nwg = gridDim.x;
    int wg = blockIdx.x;
    if ((nwg & 7) == 0)
        wg = (wg & 7) * (nwg >> 3) + (wg >> 3);
    const int bx = wg % nbx;
    const int by = wg / nbx;
    const long gm0 = (long)by * 256;
    const long gn0 = (long)bx * 256;

    const u16* A = Ap + (long)b * aBatch;
    const u16* B = Bp + (long)b * bBatch;

    const int rl = lane >> 3;                    // 0..7
    const int lsl = ((lane & 7) ^ rl) * 8;       // pre-swizzled src col (u16)
    const long aR = gm0 + wave * 8 + rl;
    const long bR = gn0 + (wave >> 2) * 64 + (wave & 3) * 8 + rl;

#define STGD(sl, tt) do { \
    const long kc_ = (long)(tt) << 6; \
    u16* l_ = &lds[sl][0][0]; \
    gld16(l_ + 0 * 8192 + wave * 512,       A + (aR)       * lda + kc_ + lsl); \
    gld16(l_ + 0 * 8192 + (8 + wave) * 512, A + (aR + 128) * lda + kc_ + lsl); \
    gld16(l_ + 1 * 8192 + wave * 512,       A + (aR + 64)  * lda + kc_ + lsl); \
    gld16(l_ + 1 * 8192 + (8 + wave) * 512, A + (aR + 192) * lda + kc_ + lsl); \
    gld16(l_ + 2 * 8192 + wave * 512,       B + (bR)       * ldb + kc_ + lsl); \
    gld16(l_ + 2 * 8192 + (8 + wave) * 512, B + (bR + 128) * ldb + kc_ + lsl); \
    gld16(l_ + 3 * 8192 + wave * 512,       B + (bR + 32)  * ldb + kc_ + lsl); \
    gld16(l_ + 3 * 8192 + (8 + wave) * 512, B + (bR + 160) * ldb + kc_ + lsl); \
} while (0)

    // read offsets (u16). 16B slot s ^= (row&7) via s0.
    const int s0 = quad ^ (m16 & 7);
    const int aBase = (wm * 64 + m16) * 64;
    const int bBase = (wn * 32 + m16) * 64;
    const int aoff0 = aBase + s0 * 8, aoff1 = aBase + (s0 ^ 4) * 8;
    const int boff0 = bBase + s0 * 8, boff1 = bBase + (s0 ^ 4) * 8;

    short8 aF[4][2], b0F[2][2], b1F[2][2];
    f32x4 acc[8][4];
    #pragma unroll
    for (int mi = 0; mi < 8; mi++)
        #pragma unroll
        for (int ni = 0; ni < 4; ni++)
            acc[mi][ni] = (f32x4){0.f, 0.f, 0.f, 0.f};

// one tile's compute from buffer sl
#define TILE_COMPUTE(sl) do { \
    const u16* l = &lds[sl][0][0]; \
    _Pragma("unroll") \
    for (int mfl = 0; mfl < 4; ++mfl) { \
        aF[mfl][0] = *(const short8*)(l + aoff0 + mfl * 1024); \
        aF[mfl][1] = *(const short8*)(l + aoff1 + mfl * 1024); \
    } \
    _Pragma("unroll") \
    for (int nj = 0; nj < 2; ++nj) { \
        b0F[nj][0] = *(const short8*)(l + 2 * 8192 + boff0 + nj * 1024); \
        b0F[nj][1] = *(const short8*)(l + 2 * 8192 + boff1 + nj * 1024); \
        b1F[nj][0] = *(const short8*)(l + 3 * 8192 + boff0 + nj * 1024); \
        b1F[nj][1] = *(const short8*)(l + 3 * 8192 + boff1 + nj * 1024); \
    } \
    _Pragma("unroll") \
    for (int mi = 0; mi < 4; ++mi) \
        _Pragma("unroll") \
        for (int nj = 0; nj < 4; ++nj) { \
            const short8* bf = (nj < 2) ? &b0F[nj][0] : &b1F[nj - 2][0]; \
            acc[mi][nj] = __builtin_amdgcn_mfma_f32_16x16x32_bf16( \
                aF[mi][0], bf[0], acc[mi][nj], 0, 0, 0); \
            acc[mi][nj] = __builtin_amdgcn_mfma_f32_16x16x32_bf16( \
                aF[mi][1], bf[1], acc[mi][nj], 0, 0, 0); \
        } \
    _Pragma("unroll") \
    for (int mfl = 0; mfl < 4; ++mfl) { \
        aF[mfl][0] = *(const short8*)(l + 1 * 8192 + aoff0 + mfl * 1024); \
        aF[mfl][1] = *(const short8*)(l + 1 * 8192 + aoff1 + mfl * 1024); \
    } \
    _Pragma("unroll") \
    for (int mi = 0; mi < 4; ++mi) \
        _Pragma("unroll") \
        for (int nj = 0; nj < 4; ++nj) { \
            const short8* bf = (nj < 2) ? &b0F[nj][0] : &b1F[nj - 2][0]; \
            acc[4 + mi][nj] = __builtin_amdgcn_mfma_f32_16x16x32_bf16( \
                aF[mi][0], bf[0], acc[4 + mi][nj], 0, 0, 0); \
            acc[4 + mi][nj] = __builtin_amdgcn_mfma_f32_16x16x32_bf16( \
                aF[mi][1], bf[1], acc[4 + mi][nj], 0, 0, 0); \
        } \
} while (0)

    // prologue
    STGD(0, 0);
    __syncthreads();

    // main loop, unrolled x2 (T even) so buffer index is compile-time
    for (int t = 0; t < T; t += 2) {
        if (t + 1 < T) STGD(1, t + 1);
        TILE_COMPUTE(0);
        __syncthreads();
        if (t + 2 < T) STGD(0, t + 2);
        TILE_COMPUTE(1);
        __syncthreads();
    }

    // epilogue: (mi,r) outer / ni inner -> 4 line-filling stores adjacent.
    const long row0 = gm0 + wm * 128 + quad * 4;
    const long colbase = gn0 + wn * 64 + m16;
    if (EPI == 0 || EPI == 1) {
        u16* C = (u16*)Cp + (long)b * cBatch;
        float bv[4];
        #pragma unroll
        for (int ni = 0; ni < 4; ++ni)
            bv[ni] = (EPI == 0 && bias)
                   ? bias[colbase + (ni >> 1) * 32 + (ni & 1) * 16] : 0.f;
        #pragma unroll
        for (int mi = 0; mi < 8; ++mi) {
            const long rb = row0 + (mi >> 2) * 64 + (mi & 3) * 16;
            #pragma unroll
            for (int r = 0; r < 4; ++r) {
                u16* Crow = C + (rb + r) * ldc + colbase;
                #pragma unroll
                for (int ni = 0; ni < 4; ++ni) {
                    const float vv = (EPI == 1) ? acc[mi][ni][r] * scale
                                                : acc[mi][ni][r] + bv[ni];
                    Crow[(ni >> 1) * 32 + (ni & 1) * 16] = f2bf(vv);
                }
            }
        }
    } else {
        float* C = (float*)Cp + (long)b * cBatch;
        float bv[4];
        #pragma unroll
        for (int ni = 0; ni < 4; ++ni)
            bv[ni] = bias ? bias[colbase + (ni >> 1) * 32 + (ni & 1) * 16] : 0.f;
        #pragma unroll
        for (int mi = 0; mi < 8; ++mi) {
            const long rb = row0 + (mi >> 2) * 64 + (mi & 3) * 16;
            #pragma unroll
            for (int r = 0; r < 4; ++r) {
                float* Crow = C + (rb + r) * ldc + colbase;
                #pragma unroll
                for (int ni = 0; ni < 4; ++ni)
                    Crow[(ni >> 1) * 32 + (ni & 1) * 16] = acc[mi][ni][r] + bv[ni];
            }
        }
    }
#undef STGD
#undef TILE_COMPUTE
}

// ============================ gemm128d =====================================
// Direct geometry reduction of gemm256d: 128x128 tile, BK=64, 256 threads
// = 4 waves (2M x 2N), per-wave 64x64 out = acc[4][4] f32x4. LDS 64 KiB =
// lds[2 buf][2 (A,B)][8192 u16] -> 2 blocks/CU (cross-block overlap).
// Same T2 swizzle, same dbuf/stage-ahead/one-sync-per-tile loop, same
// write-combined epilogue. Staging: chunk c = i*4+wave covers rows
// c*8..c*8+7 (16 chunks = 128 rows); lane rl = row-in-chunk; pre-swizzled
// source col ((lane&7)^rl)*8.
template<int EPI>
__global__ __launch_bounds__(256, 2) void gemm128d(
    const u16* __restrict__ Ap, long lda, long aBatch,
    const u16* __restrict__ Bp, long ldb, long bBatch,
    void* __restrict__ Cp, long ldc, long cBatch,
    const float* __restrict__ bias, float scale, int K, int nbx)
{
    __shared__ __attribute__((aligned(16))) u16 lds[2][2][8192];

    const int T = K >> 6;              // even
    const int tid = threadIdx.x;
    const int lane = tid & 63;
    const int wave = tid >> 6;         // 0..3
    const int wm = wave >> 1;          // 0..1
    const int wn = wave & 1;           // 0..1
    const int m16 = lane & 15;
    const int quad = lane >> 4;
    const int b = blockIdx.z;

    // T1: bijective XCD swizzle (nwg % 8 == 0 for all launches here)
    const int nwg = gridDim.x;
    int wg = blockIdx.x;
    if ((nwg & 7) == 0)
        wg = (wg & 7) * (nwg >> 3) + (wg >> 3);
    const int bx = wg % nbx;
    const int by = wg / nbx;
    const long m0 = (long)by * 128;
    const long n0 = (long)bx * 128;

    const u16* A = Ap + (long)b * aBatch;
    const u16* B = Bp + (long)b * bBatch;

    const int rl = lane >> 3;                 // 0..7
    const int lsl = ((lane & 7) ^ rl) * 8;    // pre-swizzled src col (u16)
    const long aR = m0 + wave * 8 + rl;       // + i*32
    const long bR = n0 + wave * 8 + rl;       // + i*32

#define STG128(sl, tt) do { \
    const long kc_ = (long)(tt) << 6; \
    _Pragma("unroll") \
    for (int i_ = 0; i_ < 4; ++i_) { \
        gld16(&lds[sl][0][(i_ * 4 + wave) * 512], A + (aR + i_ * 32) * lda + kc_ + lsl); \
        gld16(&lds[sl][1][(i_ * 4 + wave) * 512], B + (bR + i_ * 32) * ldb + kc_ + lsl); \
    } \
} while (0)

    // read offsets (u16). row = w?*64 + f*16 + m16; 16B slot s ^= (row&7).
    const int s0 = quad ^ (m16 & 7);
    const int aoff0 = (wm * 64 + m16) * 64 + s0 * 8;
    const int aoff1 = (wm * 64 + m16) * 64 + (s0 ^ 4) * 8;
    const int boff0 = (wn * 64 + m16) * 64 + s0 * 8;
    const int boff1 = (wn * 64 + m16) * 64 + (s0 ^ 4) * 8;

    short8 aF[4][2], bF[4][2];
    f32x4 acc[4][4];
    #pragma unroll
    for (int mi = 0; mi < 4; mi++)
        #pragma unroll
        for (int ni = 0; ni < 4; ni++)
            acc[mi][ni] = (f32x4){0.f, 0.f, 0.f, 0.f};

#define TILE128(sl) do { \
    const u16* la = &lds[sl][0][0]; \
    const u16* lb = &lds[sl][1][0]; \
    _Pragma("unroll") \
    for (int mf = 0; mf < 4; ++mf) { \
        aF[mf][0] = *(const short8*)(la + aoff0 + mf * 1024); \
        aF[mf][1] = *(const short8*)(la + aoff1 + mf * 1024); \
    } \
    _Pragma("unroll") \
    for (int nj = 0; nj < 4; ++nj) { \
        bF[nj][0] = *(const short8*)(lb + boff0 + nj * 1024); \
        bF[nj][1] = *(const short8*)(lb + boff1 + nj * 1024); \
    } \
    _Pragma("unroll") \
    for (int mi = 0; mi < 4; ++mi) \
        _Pragma("unroll") \
        for (int nj = 0; nj < 4; ++nj) { \
            acc[mi][nj] = __builtin_amdgcn_mfma_f32_16x16x32_bf16( \
                aF[mi][0], bF[nj][0], acc[mi][nj], 0, 0, 0); \
            acc[mi][nj] = __builtin_amdgcn_mfma_f32_16x16x32_bf16( \
                aF[mi][1], bF[nj][1], acc[mi][nj], 0, 0, 0); \
        } \
} while (0)

    // prologue
    STG128(0, 0);
    __syncthreads();

    for (int t = 0; t < T; t += 2) {
        if (t + 1 < T) STG128(1, t + 1);
        TILE128(0);
        __syncthreads();
        if (t + 2 < T) STG128(0, t + 2);
        TILE128(1);
        __syncthreads();
    }

    // epilogue: (mi,r) outer / ni inner (write-combining).
    const long row0 = m0 + wm * 64 + quad * 4;
    const long colbase = n0 + wn * 64 + m16;
    if (EPI == 0 || EPI == 1) {
        u16* C = (u16*)Cp + (long)b * cBatch;
        float bv[4];
        #pragma unroll
        for (int ni = 0; ni < 4; ++ni)
            bv[ni] = (EPI == 0 && bias) ? bias[colbase + ni * 16] : 0.f;
        #pragma unroll
        for (int mi = 0; mi < 4; ++mi)
            #pragma unroll
            for (int r = 0; r < 4; ++r) {
                u16* Crow = C + (row0 + mi * 16 + r) * ldc + colbase;
                #pragma unroll
                for (int ni = 0; ni < 4; ++ni) {
                    const float vv = (EPI == 1) ? acc[mi][ni][r] * scale
                                                : acc[mi][ni][r] + bv[ni];
                    Crow[ni * 16] = f2bf(vv);
                }
            }
    } else {
        float* C = (float*)Cp + (long)b * cBatch;
        float bv[4];
        #pragma unroll
        for (int ni = 0; ni < 4; ++ni)
            bv[ni] = bias ? bias[colbase + ni * 16] : 0.f;
        #pragma unroll
        for (int mi = 0; mi < 4; ++mi)
            #pragma unroll
            for (int r = 0; r < 4; ++r) {
                float* Crow = C + (row0 + mi * 16 + r) * ldc + colbase;
                #pragma unroll
                for (int ni = 0; ni < 4; ++ni)
                    Crow[ni * 16] = acc[mi][ni][r] + bv[ni];
            }
    }
#undef STG128
#undef TILE128
}

// in-place masked row softmax over 2048 bf16 (f32 math). 1 block per row.
// mask==0 -> score := 1e-10 (applied here in f32; coalesced uint4 reads).
__global__ __launch_bounds__(256) void softmax2048(u16* __restrict__ S,
                                                   const int* __restrict__ mask) {
    const long row = blockIdx.x;
    u16* p = S + row * SEQ;
    const int* mrow = mask + row * SEQ;
    const int tid = threadIdx.x;

    short8 v = *(const short8*)(p + tid * 8);
    uint4 mw0 = *(const uint4*)(mrow + tid * 8);
    uint4 mw1 = *(const uint4*)(mrow + tid * 8 + 4);
    const unsigned int* mwv = (const unsigned int*)&mw0;

    float f[8];
    #pragma unroll
    for (int j = 0; j < 8; j++) {
        const unsigned int mv = (j < 4) ? mwv[j] : ((const unsigned int*)&mw1)[j - 4];
        f[j] = (mv == 0u) ? 1e-10f : bf2f((u16)v[j]);
    }

    float m = f[0];
    #pragma unroll
    for (int j = 1; j < 8; j++) m = fmaxf(m, f[j]);
    #pragma unroll
    for (int i = 1; i < 64; i <<= 1) m = fmaxf(m, __shfl_xor(m, i));

    __shared__ float redm[4], reds[4];
    if ((tid & 63) == 0) redm[tid >> 6] = m;
    __syncthreads();
    m = fmaxf(fmaxf(redm[0], redm[1]), fmaxf(redm[2], redm[3]));

    float e[8], s = 0.f;
    #pragma unroll
    for (int j = 0; j < 8; j++) { e[j] = __expf(f[j] - m); s += e[j]; }
    #pragma unroll
    for (int i = 1; i < 64; i <<= 1) s += __shfl_xor(s, i);
    if ((tid & 63) == 0) reds[tid >> 6] = s;
    __syncthreads();
    s = reds[0] + reds[1] + reds[2] + reds[3];

    const float inv = 1.f / s;
    short8 o;
    #pragma unroll
    for (int j = 0; j < 8; j++) o[j] = (short)f2bf(e[j] * inv);
    *(short8*)(p + tid * 8) = o;
}

extern "C" void kernel_launch(void* const* d_in, const int* in_sizes, int n_in,
                              void* d_out, int out_size, void* d_ws, size_t ws_size,
                              hipStream_t stream) {
    const float* x    = (const float*)d_in[0];
    const int*   mask = (const int*)d_in[1];
    const float* Wqkv = (const float*)d_in[2];
    const float* bqkv = (const float*)d_in[3];
    const float* Wout = (const float*)d_in[4];
    const float* bout = (const float*)d_in[5];
    float* out = (float*)d_out;

    char* ws = (char*)d_ws;
    // ws layout, total 102,760,448 bytes:
    //   [0,        16777216) xh  bf16 [8192][1024]          (cvt -> K1)
    //   [16777216, 23068672) wqt bf16 [3072][1024]          (cvt -> K1)
    //   [0,        33554432) sc  bf16 [4][2048][2048]       (K2 -> K4; xh,wqt dead)
    //   [33554432, 35651584) wot bf16 [1024][1024]          (cvt -> K5)
    //   [35651584, 85983232) qkv bf16 [8192][3072]          (K1 -> K2)
    //   [35651584, 52428800) attn bf16 [8192][1024]         (K4 -> K5; qkv dead)
    //   [85983232,102760448) vt  bf16 [4][1024][2048]       (transpose_v -> K4)
    u16* xh   = (u16*)(ws + 0);
    u16* wqt  = (u16*)(ws + 16777216);
    u16* sc   = (u16*)(ws + 0);
    u16* wot  = (u16*)(ws + 33554432);
    u16* qkv  = (u16*)(ws + 35651584);
    u16* attn = (u16*)(ws + 35651584);
    u16* vt   = (u16*)(ws + 85983232);

    cvt_bf16<<<4096, 256, 0, stream>>>(x, xh, 8388608);
    transpose_cvt<<<dim3(96, 32), 256, 0, stream>>>(Wqkv, wqt, 1024, 3072);
    transpose_cvt<<<dim3(32, 32), 256, 0, stream>>>(Wout, wot, 1024, 1024);

    // K1: qkv = x @ Wqkv + bqkv (M=8192, N=3072, K=1024), bf16 out.
    // gemm256d: grid 12x32 = 384 wgs, nbx = 12.
    gemm256d<0><<<dim3(384, 1, 1), 512, 0, stream>>>(
        xh, 1024, 0, wqt, 1024, 0, qkv, 3072, 0, bqkv, 1.f, 1024, 12);

    // V slice -> vt [b][d][s]
    transpose_v<<<dim3(32, 64, NB), 256, 0, stream>>>(qkv, vt);

    // K2: sc[b] = (Q[b] @ K[b]^T)/32 (M=N=2048, K=1024), bf16 out.
    // gemm256d: 8x8 = 64 wgs/batch x 4 = 256 wgs = 1 block/CU.
    gemm256d<1><<<dim3(64, 1, NB), 512, 0, stream>>>(
        qkv, 3072, (long)SEQ * 3072, qkv + 1024, 3072, (long)SEQ * 3072,
        sc, SEQ, (long)SEQ * SEQ, nullptr, 0.03125f, 1024, 8);

    // K3: masked softmax rows (mask==0 -> 1e-10, f32 math, bf16 storage)
    softmax2048<<<dim3(NB * SEQ), 256, 0, stream>>>(sc, mask);

    // K4: attn[b] = P[b] @ V[b] (M=2048, N=1024, K=2048), bf16 out.
    // gemm128d: 8x16 = 128 wgs/batch x 4 = 512 wgs = 2 blocks/CU.
    gemm128d<0><<<dim3(128, 1, NB), 256, 0, stream>>>(
        sc, SEQ, (long)SEQ * SEQ, vt, SEQ, (long)1024 * SEQ,
        attn, 1024, (long)SEQ * 1024, nullptr, 1.f, 2048, 8);

    // K5: out = attn @ Wout + bout (M=8192, N=1024, K=1024), f32 out.
    // gemm128d: 8x64 = 512 wgs = 2 blocks/CU.
    gemm128d<2><<<dim3(512, 1, 1), 256, 0, stream>>>(
        attn, 1024, 0, wot, 1024, 0, out, 1024, 0, bout, 1.f, 1024, 8);
}